// Round 3
// baseline (955.427 us; speedup 1.0000x reference)
//
#include <hip/hip_runtime.h>
#include <math.h>

#define NN 50000
#define NE 800000

constexpr float NEG_SLOPE = 0.2f;

typedef float f32x4 __attribute__((ext_vector_type(4)));
typedef float abf   __attribute__((ext_vector_type(4)));  // 4 VGPRs = 8 bf16 bits

// D = A*B + D ; 16x16x32 bf16 MFMA via inline asm (sidesteps builtin signature).
__device__ inline void mfma16(f32x4& d, abf a, abf b)
{
    asm("v_mfma_f32_16x16x32_bf16 %0, %1, %2, %0" : "+v"(d) : "v"(a), "v"(b));
}

__device__ inline unsigned short f2bf(float x)
{
    unsigned int u = __float_as_uint(x);
    unsigned int r = (u + 0x7FFFu + ((u >> 16) & 1u)) >> 16;  // RNE
    return (unsigned short)r;
}
__device__ inline float bf2f(unsigned short b)
{
    return __uint_as_float(((unsigned int)b) << 16);
}

// ---------------------------------------------------------------------------
// split3: up to three fp32 matrices [M,K] -> bf16 hi|lo [M,2K] (hi cols 0..K-1,
// lo cols K..2K-1). K is a power of two (pass kshift). blockIdx.z selects.
// ---------------------------------------------------------------------------
__global__ __launch_bounds__(256) void split3_kernel(
    const float* __restrict__ X0, unsigned short* __restrict__ Y0, int n0, int ks0,
    const float* __restrict__ X1, unsigned short* __restrict__ Y1, int n1, int ks1,
    const float* __restrict__ X2, unsigned short* __restrict__ Y2, int n2, int ks2)
{
    const int z = blockIdx.z;
    const float* X = (z == 0) ? X0 : (z == 1) ? X1 : X2;
    unsigned short* Y = (z == 0) ? Y0 : (z == 1) ? Y1 : Y2;
    const int n = (z == 0) ? n0 : (z == 1) ? n1 : n2;       // total elements (mult of 4)
    const int ks = (z == 0) ? ks0 : (z == 1) ? ks1 : ks2;   // log2(K)
    const int K = 1 << ks;
    const int n4 = n >> 2;
    for (int i = blockIdx.x * blockDim.x + threadIdx.x; i < n4;
         i += gridDim.x * blockDim.x) {
        const float4 v = reinterpret_cast<const float4*>(X)[i];
        const int e0 = i << 2;
        const int m = e0 >> ks;
        const int k = e0 & (K - 1);
        ushort4 hi, lo;
        hi.x = f2bf(v.x); lo.x = f2bf(v.x - bf2f(hi.x));
        hi.y = f2bf(v.y); lo.y = f2bf(v.y - bf2f(hi.y));
        hi.z = f2bf(v.z); lo.z = f2bf(v.z - bf2f(hi.z));
        hi.w = f2bf(v.w); lo.w = f2bf(v.w - bf2f(hi.w));
        *reinterpret_cast<ushort4*>(&Y[(size_t)m * (2 * K) + k]) = hi;
        *reinterpret_cast<ushort4*>(&Y[(size_t)m * (2 * K) + K + k]) = lo;
    }
}

// ---------------------------------------------------------------------------
// MFMA GEMM (NT): C[m,n] = sum_k A[m,k]*B[n,k], computed in split-bf16:
//   seg0: Ahi*Bhi   seg1: Alo*Bhi   seg2: Ahi*Blo    (ll dropped, ~2^-18 rel)
// A2: [M,2K] bf16 (hi|lo), B2: [Nc,2K] bf16, C: [M,Nc] f32.
// Block = 4 waves; block tile 128x128; wave tile 64x64 = 4x4 MFMA subtiles.
// No LDS: per 16x16x32 step each lane loads one contiguous 16B A-frag and
// B-frag (row/col = lane&15, k = 8*(lane>>4)+j). B is small & cache-resident.
// Optional fused epilogue: el/er per (row, head) from C accumulators
// (wave's 64 cols == one head for layers 0/1; head 0 with F=40 for layer 2).
// ---------------------------------------------------------------------------
__global__ __launch_bounds__(256) void mfma_gemm_nt(
    const unsigned short* __restrict__ A2, const unsigned short* __restrict__ B2,
    float* __restrict__ C,
    const float* __restrict__ al, const float* __restrict__ ar,
    float* __restrict__ el, float* __restrict__ er,
    int M, int K, int Nc, int H, int F)
{
    const int lane = threadIdx.x & 63;
    const int w = threadIdx.x >> 6;
    const int m0w = blockIdx.x * 128 + (w & 1) * 64;
    const int n0w = blockIdx.y * 128 + (w >> 1) * 64;
    if (n0w >= Nc) return;  // wave-uniform; no syncs in this kernel

    const int ld = 2 * K;
    const int lr = lane & 15;          // A row / B col within 16-tile
    const int lk = (lane >> 4) * 8;    // k offset within 32-chunk

    int arow[4], bcol[4];
#pragma unroll
    for (int mi = 0; mi < 4; ++mi) arow[mi] = min(m0w + mi * 16 + lr, M - 1);
#pragma unroll
    for (int ni = 0; ni < 4; ++ni) bcol[ni] = min(n0w + ni * 16 + lr, Nc - 1);

    f32x4 acc[4][4];
#pragma unroll
    for (int mi = 0; mi < 4; ++mi)
#pragma unroll
        for (int ni = 0; ni < 4; ++ni) acc[mi][ni] = (f32x4){0.f, 0.f, 0.f, 0.f};

    for (int seg = 0; seg < 3; ++seg) {
        const int aB = (seg == 1) ? K : 0;
        const int bB = (seg == 2) ? K : 0;
        for (int k0 = 0; k0 < K; k0 += 32) {
            abf a[4], b[4];
#pragma unroll
            for (int mi = 0; mi < 4; ++mi)
                a[mi] = *reinterpret_cast<const abf*>(
                    &A2[(size_t)arow[mi] * ld + aB + k0 + lk]);
#pragma unroll
            for (int ni = 0; ni < 4; ++ni)
                b[ni] = *reinterpret_cast<const abf*>(
                    &B2[(size_t)bcol[ni] * ld + bB + k0 + lk]);
#pragma unroll
            for (int mi = 0; mi < 4; ++mi)
#pragma unroll
                for (int ni = 0; ni < 4; ++ni) mfma16(acc[mi][ni], a[mi], b[ni]);
        }
    }

    // MFMA -> VALU/VMEM read hazard: pin nops here (asm is opaque to the
    // hazard recognizer).
    __builtin_amdgcn_sched_barrier(0);
    asm volatile("s_nop 7\n\ts_nop 7");
    __builtin_amdgcn_sched_barrier(0);

    // ---- store C ----  lane holds C[row=(lane>>4)*4+r][col=lane&15] per tile
#pragma unroll
    for (int mi = 0; mi < 4; ++mi) {
#pragma unroll
        for (int ni = 0; ni < 4; ++ni) {
            const int col = n0w + ni * 16 + lr;
            if (col >= Nc) continue;
#pragma unroll
            for (int r = 0; r < 4; ++r) {
                const int row = m0w + mi * 16 + (lane >> 4) * 4 + r;
                if (row < M) C[(size_t)row * Nc + col] = acc[mi][ni][r];
            }
        }
    }

    // ---- fused el/er epilogue ----
    if (el != nullptr) {
        const int head = n0w >> 6;  // 64 cols per head; layer2: head 0 only
        if (head < H) {
            float alv[4], arv[4];
#pragma unroll
            for (int ni = 0; ni < 4; ++ni) {
                const int f = ni * 16 + lr;
                alv[ni] = (f < F) ? al[head * F + f] : 0.f;
                arv[ni] = (f < F) ? ar[head * F + f] : 0.f;
            }
#pragma unroll
            for (int mi = 0; mi < 4; ++mi) {
#pragma unroll
                for (int r = 0; r < 4; ++r) {
                    float dl = 0.f, dr = 0.f;
#pragma unroll
                    for (int ni = 0; ni < 4; ++ni) {
                        dl += acc[mi][ni][r] * alv[ni];
                        dr += acc[mi][ni][r] * arv[ni];
                    }
#pragma unroll
                    for (int o = 1; o < 16; o <<= 1) {
                        dl += __shfl_xor(dl, o);
                        dr += __shfl_xor(dr, o);
                    }
                    const int row = m0w + mi * 16 + (lane >> 4) * 4 + r;
                    if (lr == 0 && row < M) {
                        el[(size_t)row * H + head] = dl;
                        er[(size_t)row * H + head] = dr;
                    }
                }
            }
        }
    }
}

// ---------------------------------------------------------------------------
// CSR build: histogram -> single-block wave-shuffle scan -> scatter
// ---------------------------------------------------------------------------
__global__ void hist_kernel(const int* __restrict__ dst, int* __restrict__ deg, int E)
{
    const int i = blockIdx.x * blockDim.x + threadIdx.x;
    if (i < E) atomicAdd(&deg[dst[i]], 1);
}

__global__ __launch_bounds__(1024) void scan_kernel(const int* __restrict__ deg,
                                                    int* __restrict__ offs,
                                                    int* __restrict__ cursor, int N)
{
    __shared__ int wsums[16];
    __shared__ int carry_s;
    const int tid = threadIdx.x;
    const int lane = tid & 63;
    const int wv = tid >> 6;
    if (tid == 0) carry_s = 0;
    __syncthreads();
    for (int base = 0; base < N; base += 1024) {
        const int i = base + tid;
        const int v = (i < N) ? deg[i] : 0;
        int x = v;  // inclusive scan within wave
#pragma unroll
        for (int o = 1; o < 64; o <<= 1) {
            const int t = __shfl_up(x, o);
            if (lane >= o) x += t;
        }
        if (lane == 63) wsums[wv] = x;
        __syncthreads();
        if (wv == 0) {
            int wsv = (lane < 16) ? wsums[lane] : 0;
#pragma unroll
            for (int o = 1; o < 16; o <<= 1) {
                const int t = __shfl_up(wsv, o);
                if (lane >= o) wsv += t;
            }
            if (lane < 16) wsums[lane] = wsv;  // inclusive over waves
        }
        __syncthreads();
        const int wexcl = (wv == 0) ? 0 : wsums[wv - 1];
        const int c = carry_s;
        const int excl = c + wexcl + (x - v);
        if (i < N) { offs[i] = excl; cursor[i] = excl; }
        __syncthreads();
        if (tid == 1023) carry_s = c + wsums[15];
        __syncthreads();
    }
    if (tid == 0) offs[N] = carry_s;
}

__global__ void scatter_kernel(const int* __restrict__ src, const int* __restrict__ dst,
                               int* __restrict__ cursor, int* __restrict__ csrc, int E)
{
    const int i = blockIdx.x * blockDim.x + threadIdx.x;
    if (i < E) {
        const int d = dst[i];
        const int pos = atomicAdd(&cursor[d], 1);
        csrc[pos] = src[i];
    }
}

// ---------------------------------------------------------------------------
// GAT aggregation, online-softmax single pass. Wave per destination node.
// ---------------------------------------------------------------------------
template <int H, int F, bool DO_ELU>
__global__ __launch_bounds__(256) void gat_agg(const float* __restrict__ Hb,
                                               const float* __restrict__ el,
                                               const float* __restrict__ er,
                                               const int* __restrict__ offs,
                                               const int* __restrict__ csrc,
                                               float* __restrict__ Y, int N)
{
    constexpr int HF = H * F;
    constexpr int CS = 64 / H;  // edges per chunk
    constexpr bool VEC4 = (HF == 256);
    const int node = blockIdx.x * 4 + (threadIdx.x >> 6);
    const int lane = threadIdx.x & 63;
    if (node >= N) return;
    const int off = offs[node];
    const int deg = offs[node + 1] - off;
    const int edge_sl = lane & (CS - 1);
    const int head = lane / CS;          // 0 for H==1
    const int gbase = lane & ~(CS - 1);  // group base lane

    const float erh = er[(size_t)node * H + head];

    float m = -INFINITY;
    float dsum = 0.f;
    float acc0 = 0.f, acc1 = 0.f, acc2 = 0.f, acc3 = 0.f;

    for (int base = 0; base < deg; base += CS) {
        const int cnt = min(CS, deg - base);
        int s_reg = 0;
        float sv = -INFINITY;
        if (edge_sl < cnt) {
            s_reg = csrc[off + base + edge_sl];
            const float x = el[(size_t)s_reg * H + head] + erh;
            sv = (x >= 0.f) ? x : NEG_SLOPE * x;
        }
        float cm = sv;
#pragma unroll
        for (int o = 1; o < CS; o <<= 1) cm = fmaxf(cm, __shfl_xor(cm, o));
        const float mn = fmaxf(m, cm);
        const float sc = __expf(m - mn);  // first chunk: exp(-inf)=0
        dsum *= sc; acc0 *= sc; acc1 *= sc; acc2 *= sc; acc3 *= sc;
        m = mn;
        const float p = (edge_sl < cnt) ? __expf(sv - mn) : 0.f;
        dsum += p;

        for (int e = 0; e < cnt; ++e) {
            const float pe = __shfl(p, gbase + e);
            const int se = __shfl(s_reg, gbase + e);
            if (VEC4) {
                const float4 hv =
                    *reinterpret_cast<const float4*>(&Hb[(size_t)se * HF + lane * 4]);
                acc0 += pe * hv.x; acc1 += pe * hv.y;
                acc2 += pe * hv.z; acc3 += pe * hv.w;
            } else {
                if (lane < HF) acc0 += pe * Hb[(size_t)se * HF + lane];
            }
        }
    }

#pragma unroll
    for (int o = 1; o < CS; o <<= 1) dsum += __shfl_xor(dsum, o);
    const float inv = (dsum > 0.f) ? 1.f / dsum : 0.f;

    if (VEC4) {
        float4 r = *reinterpret_cast<const float4*>(&Y[(size_t)node * HF + lane * 4]);
        float o0 = acc0 * inv + r.x;
        float o1 = acc1 * inv + r.y;
        float o2 = acc2 * inv + r.z;
        float o3 = acc3 * inv + r.w;
        if (DO_ELU) {
            o0 = (o0 > 0.f) ? o0 : expm1f(o0);
            o1 = (o1 > 0.f) ? o1 : expm1f(o1);
            o2 = (o2 > 0.f) ? o2 : expm1f(o2);
            o3 = (o3 > 0.f) ? o3 : expm1f(o3);
        }
        *reinterpret_cast<float4*>(&Y[(size_t)node * HF + lane * 4]) =
            make_float4(o0, o1, o2, o3);
    } else if (lane < HF) {
        float o = acc0 * inv + Y[(size_t)node * HF + lane];
        if (DO_ELU) o = (o > 0.f) ? o : expm1f(o);
        Y[(size_t)node * HF + lane] = o;
    }
}

// ---------------------------------------------------------------------------
extern "C" void kernel_launch(void* const* d_in, const int* in_sizes, int n_in,
                              void* d_out, int out_size, void* d_ws, size_t ws_size,
                              hipStream_t stream)
{
    const float* feat = (const float*)d_in[0];
    const int* src = (const int*)d_in[1];
    const int* dst = (const int*)d_in[2];
    const float* W0 = (const float*)d_in[3];
    const float* al0 = (const float*)d_in[4];
    const float* ar0 = (const float*)d_in[5];
    const float* rW0 = (const float*)d_in[6];
    const float* W1 = (const float*)d_in[7];
    const float* al1 = (const float*)d_in[8];
    const float* ar1 = (const float*)d_in[9];
    const float* rW1 = (const float*)d_in[10];
    const float* W2 = (const float*)d_in[11];
    const float* al2 = (const float*)d_in[12];
    const float* ar2 = (const float*)d_in[13];
    const float* rW2 = (const float*)d_in[14];
    float* out = (float*)d_out;

    char* ws = (char*)d_ws;
    size_t o = 0;
    auto alloc = [&](size_t bytes) -> void* {
        void* p = ws + o;
        o += (bytes + 255) & ~(size_t)255;
        return p;
    };
    unsigned short* A2 = (unsigned short*)alloc((size_t)NN * 512 * 2);  // hi|lo
    float* bufH = (float*)alloc((size_t)NN * 256 * 4);                  // h (per layer)
    float* bufB = (float*)alloc((size_t)NN * 256 * 4);                  // layer-0 out
    float* bufC = (float*)alloc((size_t)NN * 256 * 4);                  // layer-1 out
    unsigned short* W0s = (unsigned short*)alloc((size_t)256 * 256 * 2);
    unsigned short* rW0s = (unsigned short*)alloc((size_t)256 * 256 * 2);
    unsigned short* W1s = (unsigned short*)alloc((size_t)256 * 512 * 2);
    unsigned short* rW1s = (unsigned short*)alloc((size_t)256 * 512 * 2);
    unsigned short* W2s = (unsigned short*)alloc((size_t)40 * 512 * 2);
    unsigned short* rW2s = (unsigned short*)alloc((size_t)40 * 512 * 2);
    float* el = (float*)alloc((size_t)NN * 4 * 4);
    float* er = (float*)alloc((size_t)NN * 4 * 4);
    int* deg = (int*)alloc((size_t)NN * 4);
    int* offs = (int*)alloc((size_t)(NN + 1) * 4);
    int* cursor = (int*)alloc((size_t)NN * 4);
    int* csrc = (int*)alloc((size_t)NE * 4);

    // ---- CSR build (by dst), shared across all 3 layers ----
    hipMemsetAsync(deg, 0, NN * sizeof(int), stream);
    hist_kernel<<<(NE + 255) / 256, 256, 0, stream>>>(dst, deg, NE);
    scan_kernel<<<1, 1024, 0, stream>>>(deg, offs, cursor, NN);
    scatter_kernel<<<(NE + 255) / 256, 256, 0, stream>>>(src, dst, cursor, csrc, NE);

    const int nodeBlocks = (NN + 3) / 4;
    const dim3 splitG(768, 1, 3);
    const int gx = (NN + 127) / 128;

    // ---- layer 0: in=128 (ks=7), H=4, F=64, Nc=256 ----
    split3_kernel<<<splitG, 256, 0, stream>>>(feat, A2, NN * 128, 7,
                                              W0, W0s, 256 * 128, 7,
                                              rW0, rW0s, 256 * 128, 7);
    {
        dim3 g(gx, 2);
        mfma_gemm_nt<<<g, 256, 0, stream>>>(A2, W0s, bufH, al0, ar0, el, er,
                                            NN, 128, 256, 4, 64);
        mfma_gemm_nt<<<g, 256, 0, stream>>>(A2, rW0s, bufB, nullptr, nullptr,
                                            nullptr, nullptr, NN, 128, 256, 4, 64);
        gat_agg<4, 64, true><<<nodeBlocks, 256, 0, stream>>>(bufH, el, er, offs, csrc, bufB, NN);
    }
    // ---- layer 1: in=256 (ks=8), H=4, F=64, Nc=256 ----
    split3_kernel<<<splitG, 256, 0, stream>>>(bufB, A2, NN * 256, 8,
                                              W1, W1s, 256 * 256, 8,
                                              rW1, rW1s, 256 * 256, 8);
    {
        dim3 g(gx, 2);
        mfma_gemm_nt<<<g, 256, 0, stream>>>(A2, W1s, bufH, al1, ar1, el, er,
                                            NN, 256, 256, 4, 64);
        mfma_gemm_nt<<<g, 256, 0, stream>>>(A2, rW1s, bufC, nullptr, nullptr,
                                            nullptr, nullptr, NN, 256, 256, 4, 64);
        gat_agg<4, 64, true><<<nodeBlocks, 256, 0, stream>>>(bufH, el, er, offs, csrc, bufC, NN);
    }
    // ---- layer 2 (output): in=256 (ks=8), H=1, F=40, Nc=40 ----
    split3_kernel<<<splitG, 256, 0, stream>>>(bufC, A2, NN * 256, 8,
                                              W2, W2s, 40 * 256, 8,
                                              rW2, rW2s, 40 * 256, 8);
    {
        dim3 g(gx, 1);
        mfma_gemm_nt<<<g, 256, 0, stream>>>(A2, W2s, bufH, al2, ar2, el, er,
                                            NN, 256, 40, 1, 40);
        mfma_gemm_nt<<<g, 256, 0, stream>>>(A2, rW2s, out, nullptr, nullptr,
                                            nullptr, nullptr, NN, 256, 40, 1, 40);
        gat_agg<1, 40, false><<<nodeBlocks, 256, 0, stream>>>(bufH, el, er, offs, csrc, out, NN);
    }
}

// Round 7
// 781.766 us; speedup vs baseline: 1.2221x; 1.2221x over previous
//
#include <hip/hip_runtime.h>
#include <math.h>

#define NN 50000
#define NE 800000

constexpr float NEG_SLOPE = 0.2f;

typedef float f32x4 __attribute__((ext_vector_type(4)));
typedef float abf   __attribute__((ext_vector_type(4)));  // 4 VGPRs = 8 bf16

// D = A*B + D ; 16x16x32 bf16 MFMA via inline asm (validated round 3).
__device__ inline void mfma16(f32x4& d, abf a, abf b)
{
    asm("v_mfma_f32_16x16x32_bf16 %0, %1, %2, %0" : "+v"(d) : "v"(a), "v"(b));
}

__device__ inline unsigned short f2bf(float x)
{
    unsigned int u = __float_as_uint(x);
    unsigned int r = (u + 0x7FFFu + ((u >> 16) & 1u)) >> 16;  // RNE
    return (unsigned short)r;
}
__device__ inline float bf2f(unsigned short b)
{
    return __uint_as_float(((unsigned int)b) << 16);
}

// ---------------------------------------------------------------------------
// split3: three fp32 matrices [M,K] -> bf16 hi|lo [M,2K]. K pow2 (kshift).
// ---------------------------------------------------------------------------
__global__ __launch_bounds__(256) void split3_kernel(
    const float* __restrict__ X0, unsigned short* __restrict__ Y0, int n0, int ks0,
    const float* __restrict__ X1, unsigned short* __restrict__ Y1, int n1, int ks1,
    const float* __restrict__ X2, unsigned short* __restrict__ Y2, int n2, int ks2)
{
    const int z = blockIdx.z;
    const float* X = (z == 0) ? X0 : (z == 1) ? X1 : X2;
    unsigned short* Y = (z == 0) ? Y0 : (z == 1) ? Y1 : Y2;
    const int n = (z == 0) ? n0 : (z == 1) ? n1 : n2;
    const int ks = (z == 0) ? ks0 : (z == 1) ? ks1 : ks2;
    const int K = 1 << ks;
    const int n4 = n >> 2;
    for (int i = blockIdx.x * blockDim.x + threadIdx.x; i < n4;
         i += gridDim.x * blockDim.x) {
        const float4 v = reinterpret_cast<const float4*>(X)[i];
        const int e0 = i << 2;
        const int m = e0 >> ks;
        const int k = e0 & (K - 1);
        ushort4 hi, lo;
        hi.x = f2bf(v.x); lo.x = f2bf(v.x - bf2f(hi.x));
        hi.y = f2bf(v.y); lo.y = f2bf(v.y - bf2f(hi.y));
        hi.z = f2bf(v.z); lo.z = f2bf(v.z - bf2f(hi.z));
        hi.w = f2bf(v.w); lo.w = f2bf(v.w - bf2f(hi.w));
        *reinterpret_cast<ushort4*>(&Y[(size_t)m * (2 * K) + k]) = hi;
        *reinterpret_cast<ushort4*>(&Y[(size_t)m * (2 * K) + K + k]) = lo;
    }
}

// ---------------------------------------------------------------------------
// Dual MFMA GEMM (NT), split-bf16 (segs: AhiBhi, AloBhi, AhiBlo):
//   C1 = A*B1^T, C2 = A*B2^T   (shared A fragments, 2-deep reg pipeline)
// Geometry: 4 waves/block. n-split (wm=0,wn=64): waves share 64 A-rows and
// cover 256 cols. m-split (wm=64,wn=0): waves cover 256 rows, cols 0..63.
// cs = log2(K/32). Fused el/er epilogue from C1 acc (head = wave's n0w>>6).
// ---------------------------------------------------------------------------
__global__ __launch_bounds__(256, 2) void mfma_gemm_dual(
    const unsigned short* __restrict__ A2, const unsigned short* __restrict__ B1b,
    const unsigned short* __restrict__ B2b,
    float* __restrict__ C1, float* __restrict__ C2,
    const float* __restrict__ al, const float* __restrict__ ar,
    float* __restrict__ el, float* __restrict__ er,
    int M, int K, int Nc, int H, int F, int wm, int wn, int cs)
{
    const int lane = threadIdx.x & 63;
    const int w = threadIdx.x >> 6;
    const int bm = blockIdx.x * (wm ? (4 * wm) : 64);
    const int m0w = bm + w * wm;
    const int n0w = w * wn;
    const int ld = 2 * K;
    const int lr = lane & 15;
    const int lk = (lane >> 4) * 8;

    int arow[4], bcol[4];
#pragma unroll
    for (int mi = 0; mi < 4; ++mi) arow[mi] = min(m0w + mi * 16 + lr, M - 1);
#pragma unroll
    for (int ni = 0; ni < 4; ++ni) bcol[ni] = min(n0w + ni * 16 + lr, Nc - 1);

    f32x4 acc1[4][4], acc2[4][4];
#pragma unroll
    for (int mi = 0; mi < 4; ++mi)
#pragma unroll
        for (int ni = 0; ni < 4; ++ni) {
            acc1[mi][ni] = (f32x4){0.f, 0.f, 0.f, 0.f};
            acc2[mi][ni] = (f32x4){0.f, 0.f, 0.f, 0.f};
        }

    const int nchunk = 1 << cs;
    const int nIt = 3 * nchunk;  // even (12 or 24)

#define LOAD_FRAGS(IT, A_, B1_, B2_)                                              \
    do {                                                                          \
        const int seg_ = (IT) >> cs;                                              \
        const int ch_ = (IT) & (nchunk - 1);                                      \
        const int aO_ = ((seg_ == 1) ? K : 0) + ch_ * 32 + lk;                    \
        const int bO_ = ((seg_ == 2) ? K : 0) + ch_ * 32 + lk;                    \
        _Pragma("unroll") for (int mi = 0; mi < 4; ++mi)                          \
            A_[mi] = *reinterpret_cast<const abf*>(                               \
                &A2[(size_t)arow[mi] * ld + aO_]);                                \
        _Pragma("unroll") for (int ni = 0; ni < 4; ++ni) {                        \
            B1_[ni] = *reinterpret_cast<const abf*>(                              \
                &B1b[(size_t)bcol[ni] * ld + bO_]);                               \
            B2_[ni] = *reinterpret_cast<const abf*>(                              \
                &B2b[(size_t)bcol[ni] * ld + bO_]);                               \
        }                                                                         \
    } while (0)

#define DO_MFMA(A_, B1_, B2_)                                                     \
    do {                                                                          \
        _Pragma("unroll") for (int mi = 0; mi < 4; ++mi)                          \
            _Pragma("unroll") for (int ni = 0; ni < 4; ++ni)                      \
                mfma16(acc1[mi][ni], A_[mi], B1_[ni]);                            \
        _Pragma("unroll") for (int mi = 0; mi < 4; ++mi)                          \
            _Pragma("unroll") for (int ni = 0; ni < 4; ++ni)                      \
                mfma16(acc2[mi][ni], A_[mi], B2_[ni]);                            \
    } while (0)

    abf aF0[4], b1F0[4], b2F0[4];
    abf aF1[4], b1F1[4], b2F1[4];

    LOAD_FRAGS(0, aF0, b1F0, b2F0);
    for (int it = 0; it < nIt; it += 2) {
        LOAD_FRAGS(it + 1, aF1, b1F1, b2F1);
        DO_MFMA(aF0, b1F0, b2F0);
        if (it + 2 < nIt) LOAD_FRAGS(it + 2, aF0, b1F0, b2F0);
        DO_MFMA(aF1, b1F1, b2F1);
    }
#undef LOAD_FRAGS
#undef DO_MFMA

    // MFMA (inline asm, opaque to hazard recognizer) -> VALU/VMEM read guard.
    __builtin_amdgcn_sched_barrier(0);
    asm volatile("s_nop 7\n\ts_nop 7");
    __builtin_amdgcn_sched_barrier(0);

    // ---- store C1/C2 ----  lane holds C[row=(lane>>4)*4+r][col=lane&15]
#pragma unroll
    for (int mi = 0; mi < 4; ++mi) {
#pragma unroll
        for (int ni = 0; ni < 4; ++ni) {
            const int col = n0w + ni * 16 + lr;
            if (col >= Nc) continue;
#pragma unroll
            for (int r = 0; r < 4; ++r) {
                const int row = m0w + mi * 16 + (lane >> 4) * 4 + r;
                if (row < M) {
                    C1[(size_t)row * Nc + col] = acc1[mi][ni][r];
                    C2[(size_t)row * Nc + col] = acc2[mi][ni][r];
                }
            }
        }
    }

    // ---- fused el/er epilogue (from C1 = W-GEMM accumulators) ----
    if (el != nullptr) {
        const int head = n0w >> 6;
        if (head < H) {
            float alv[4], arv[4];
#pragma unroll
            for (int ni = 0; ni < 4; ++ni) {
                const int f = ni * 16 + lr;
                alv[ni] = (f < F) ? al[head * F + f] : 0.f;
                arv[ni] = (f < F) ? ar[head * F + f] : 0.f;
            }
#pragma unroll
            for (int mi = 0; mi < 4; ++mi) {
#pragma unroll
                for (int r = 0; r < 4; ++r) {
                    float dl = 0.f, dr = 0.f;
#pragma unroll
                    for (int ni = 0; ni < 4; ++ni) {
                        dl += acc1[mi][ni][r] * alv[ni];
                        dr += acc1[mi][ni][r] * arv[ni];
                    }
#pragma unroll
                    for (int o = 1; o < 16; o <<= 1) {
                        dl += __shfl_xor(dl, o);
                        dr += __shfl_xor(dr, o);
                    }
                    const int row = m0w + mi * 16 + (lane >> 4) * 4 + r;
                    if (lr == 0 && row < M) {
                        el[(size_t)row * H + head] = dl;
                        er[(size_t)row * H + head] = dr;
                    }
                }
            }
        }
    }
}

// ---------------------------------------------------------------------------
// CSR build: histogram -> hierarchical scan (3 small kernels) -> scatter
// ---------------------------------------------------------------------------
__global__ void hist_kernel(const int* __restrict__ dst, int* __restrict__ deg, int E)
{
    const int i = blockIdx.x * blockDim.x + threadIdx.x;
    if (i < E) atomicAdd(&deg[dst[i]], 1);
}

__global__ __launch_bounds__(1024) void scan_part(const int* __restrict__ deg,
                                                  int* __restrict__ psum, int N)
{
    __shared__ int wsum[16];
    const int i = blockIdx.x * 1024 + threadIdx.x;
    const int lane = threadIdx.x & 63;
    const int wv = threadIdx.x >> 6;
    int s = (i < N) ? deg[i] : 0;
#pragma unroll
    for (int o = 1; o < 64; o <<= 1) s += __shfl_xor(s, o);
    if (lane == 0) wsum[wv] = s;
    __syncthreads();
    if (threadIdx.x == 0) {
        int t = 0;
#pragma unroll
        for (int k = 0; k < 16; ++k) t += wsum[k];
        psum[blockIdx.x] = t;
    }
}

__global__ void scan_tops(int* __restrict__ psum, int* __restrict__ offs, int nb, int N)
{
    const int lane = threadIdx.x;  // 64 threads, nb <= 64
    const int v = (lane < nb) ? psum[lane] : 0;
    int x = v;
#pragma unroll
    for (int o = 1; o < 64; o <<= 1) {
        const int t = __shfl_up(x, o);
        if (lane >= o) x += t;
    }
    if (lane < nb) psum[lane] = x - v;  // exclusive
    if (lane == nb - 1) offs[N] = x;    // grand total
}

__global__ __launch_bounds__(1024) void scan_final(const int* __restrict__ deg,
                                                   const int* __restrict__ psum,
                                                   int* __restrict__ offs,
                                                   int* __restrict__ cursor, int N)
{
    __shared__ int wsums[16];
    const int i = blockIdx.x * 1024 + threadIdx.x;
    const int lane = threadIdx.x & 63;
    const int wv = threadIdx.x >> 6;
    const int v = (i < N) ? deg[i] : 0;
    int x = v;
#pragma unroll
    for (int o = 1; o < 64; o <<= 1) {
        const int t = __shfl_up(x, o);
        if (lane >= o) x += t;
    }
    if (lane == 63) wsums[wv] = x;
    __syncthreads();
    if (wv == 0) {
        int wsv = (lane < 16) ? wsums[lane] : 0;
#pragma unroll
        for (int o = 1; o < 16; o <<= 1) {
            const int t = __shfl_up(wsv, o);
            if (lane >= o) wsv += t;
        }
        if (lane < 16) wsums[lane] = wsv;
    }
    __syncthreads();
    const int wexcl = (wv == 0) ? 0 : wsums[wv - 1];
    const int excl = psum[blockIdx.x] + wexcl + (x - v);
    if (i < N) { offs[i] = excl; cursor[i] = excl; }
}

__global__ void scatter_kernel(const int* __restrict__ src, const int* __restrict__ dst,
                               int* __restrict__ cursor, int* __restrict__ csrc, int E)
{
    const int i = blockIdx.x * blockDim.x + threadIdx.x;
    if (i < E) {
        const int d = dst[i];
        const int pos = atomicAdd(&cursor[d], 1);
        csrc[pos] = src[i];
    }
}

// ---------------------------------------------------------------------------
// GAT aggregation, online-softmax single pass. Wave per destination node.
// Inner accumulate unrolled x2 for memory-level parallelism.
// ---------------------------------------------------------------------------
template <int H, int F, bool DO_ELU>
__global__ __launch_bounds__(256) void gat_agg(const float* __restrict__ Hb,
                                               const float* __restrict__ el,
                                               const float* __restrict__ er,
                                               const int* __restrict__ offs,
                                               const int* __restrict__ csrc,
                                               float* __restrict__ Y, int N)
{
    constexpr int HF = H * F;
    constexpr int CS = 64 / H;
    constexpr bool VEC4 = (HF == 256);
    const int node = blockIdx.x * 4 + (threadIdx.x >> 6);
    const int lane = threadIdx.x & 63;
    if (node >= N) return;
    // clamped (robust against profiler replay with stale ws)
    int off = offs[node], end = offs[node + 1];
    off = max(0, min(off, NE));
    end = max(off, min(end, NE));
    const int deg = end - off;
    const int edge_sl = lane & (CS - 1);
    const int head = lane / CS;
    const int gbase = lane & ~(CS - 1);

    const float erh = er[(size_t)node * H + head];

    float m = -INFINITY;
    float dsum = 0.f;
    float acc0 = 0.f, acc1 = 0.f, acc2 = 0.f, acc3 = 0.f;

    for (int base = 0; base < deg; base += CS) {
        const int cnt = min(CS, deg - base);
        int s_reg = 0;
        float sv = -INFINITY;
        if (edge_sl < cnt) {
            s_reg = min(max(csrc[off + base + edge_sl], 0), N - 1);
            const float x = el[(size_t)s_reg * H + head] + erh;
            sv = (x >= 0.f) ? x : NEG_SLOPE * x;
        }
        float cm = sv;
#pragma unroll
        for (int o = 1; o < CS; o <<= 1) cm = fmaxf(cm, __shfl_xor(cm, o));
        const float mn = fmaxf(m, cm);
        const float sc = __expf(m - mn);  // first chunk: exp(-inf)=0
        dsum *= sc; acc0 *= sc; acc1 *= sc; acc2 *= sc; acc3 *= sc;
        m = mn;
        const float p = (edge_sl < cnt) ? __expf(sv - mn) : 0.f;
        dsum += p;

        int e = 0;
        for (; e + 1 < cnt; e += 2) {
            const float pe0 = __shfl(p, gbase + e);
            const int se0 = __shfl(s_reg, gbase + e);
            const float pe1 = __shfl(p, gbase + e + 1);
            const int se1 = __shfl(s_reg, gbase + e + 1);
            if (VEC4) {
                const float4 h0 =
                    *reinterpret_cast<const float4*>(&Hb[(size_t)se0 * HF + lane * 4]);
                const float4 h1 =
                    *reinterpret_cast<const float4*>(&Hb[(size_t)se1 * HF + lane * 4]);
                acc0 += pe0 * h0.x; acc1 += pe0 * h0.y;
                acc2 += pe0 * h0.z; acc3 += pe0 * h0.w;
                acc0 += pe1 * h1.x; acc1 += pe1 * h1.y;
                acc2 += pe1 * h1.z; acc3 += pe1 * h1.w;
            } else if (lane < HF) {
                const float v0 = Hb[(size_t)se0 * HF + lane];
                const float v1 = Hb[(size_t)se1 * HF + lane];
                acc0 += pe0 * v0 + pe1 * v1;
            }
        }
        if (e < cnt) {
            const float pe = __shfl(p, gbase + e);
            const int se = __shfl(s_reg, gbase + e);
            if (VEC4) {
                const float4 hv =
                    *reinterpret_cast<const float4*>(&Hb[(size_t)se * HF + lane * 4]);
                acc0 += pe * hv.x; acc1 += pe * hv.y;
                acc2 += pe * hv.z; acc3 += pe * hv.w;
            } else if (lane < HF) {
                acc0 += pe * Hb[(size_t)se * HF + lane];
            }
        }
    }

#pragma unroll
    for (int o = 1; o < CS; o <<= 1) dsum += __shfl_xor(dsum, o);
    const float inv = (dsum > 0.f) ? 1.f / dsum : 0.f;

    if (VEC4) {
        float4 r = *reinterpret_cast<const float4*>(&Y[(size_t)node * HF + lane * 4]);
        float o0 = acc0 * inv + r.x;
        float o1 = acc1 * inv + r.y;
        float o2 = acc2 * inv + r.z;
        float o3 = acc3 * inv + r.w;
        if (DO_ELU) {
            o0 = (o0 > 0.f) ? o0 : expm1f(o0);
            o1 = (o1 > 0.f) ? o1 : expm1f(o1);
            o2 = (o2 > 0.f) ? o2 : expm1f(o2);
            o3 = (o3 > 0.f) ? o3 : expm1f(o3);
        }
        *reinterpret_cast<float4*>(&Y[(size_t)node * HF + lane * 4]) =
            make_float4(o0, o1, o2, o3);
    } else if (lane < HF) {
        float o = acc0 * inv + Y[(size_t)node * HF + lane];
        if (DO_ELU) o = (o > 0.f) ? o : expm1f(o);
        Y[(size_t)node * HF + lane] = o;
    }
}

// ---------------------------------------------------------------------------
extern "C" void kernel_launch(void* const* d_in, const int* in_sizes, int n_in,
                              void* d_out, int out_size, void* d_ws, size_t ws_size,
                              hipStream_t stream)
{
    const float* feat = (const float*)d_in[0];
    const int* src = (const int*)d_in[1];
    const int* dst = (const int*)d_in[2];
    const float* W0 = (const float*)d_in[3];
    const float* al0 = (const float*)d_in[4];
    const float* ar0 = (const float*)d_in[5];
    const float* rW0 = (const float*)d_in[6];
    const float* W1 = (const float*)d_in[7];
    const float* al1 = (const float*)d_in[8];
    const float* ar1 = (const float*)d_in[9];
    const float* rW1 = (const float*)d_in[10];
    const float* W2 = (const float*)d_in[11];
    const float* al2 = (const float*)d_in[12];
    const float* ar2 = (const float*)d_in[13];
    const float* rW2 = (const float*)d_in[14];
    float* out = (float*)d_out;

    char* ws = (char*)d_ws;
    size_t o = 0;
    auto alloc = [&](size_t bytes) -> void* {
        void* p = ws + o;
        o += (bytes + 255) & ~(size_t)255;
        return p;
    };
    unsigned short* A2 = (unsigned short*)alloc((size_t)NN * 512 * 2);  // hi|lo
    float* bufH = (float*)alloc((size_t)NN * 256 * 4);
    float* bufB = (float*)alloc((size_t)NN * 256 * 4);
    float* bufC = (float*)alloc((size_t)NN * 256 * 4);
    unsigned short* W0s = (unsigned short*)alloc((size_t)256 * 256 * 2);
    unsigned short* rW0s = (unsigned short*)alloc((size_t)256 * 256 * 2);
    unsigned short* W1s = (unsigned short*)alloc((size_t)256 * 512 * 2);
    unsigned short* rW1s = (unsigned short*)alloc((size_t)256 * 512 * 2);
    unsigned short* W2s = (unsigned short*)alloc((size_t)40 * 512 * 2);
    unsigned short* rW2s = (unsigned short*)alloc((size_t)40 * 512 * 2);
    float* el = (float*)alloc((size_t)NN * 4 * 4);
    float* er = (float*)alloc((size_t)NN * 4 * 4);
    int* deg = (int*)alloc((size_t)NN * 4);
    int* offs = (int*)alloc((size_t)(NN + 1) * 4);
    int* cursor = (int*)alloc((size_t)NN * 4);
    int* psum = (int*)alloc((size_t)64 * 4);
    int* csrc = (int*)alloc((size_t)NE * 4);

    // ---- CSR build (by dst), shared across all 3 layers ----
    const int nb = (NN + 1023) / 1024;  // 49
    hipMemsetAsync(deg, 0, NN * sizeof(int), stream);
    hist_kernel<<<(NE + 255) / 256, 256, 0, stream>>>(dst, deg, NE);
    scan_part<<<nb, 1024, 0, stream>>>(deg, psum, NN);
    scan_tops<<<1, 64, 0, stream>>>(psum, offs, nb, NN);
    scan_final<<<nb, 1024, 0, stream>>>(deg, psum, offs, cursor, NN);
    scatter_kernel<<<(NE + 255) / 256, 256, 0, stream>>>(src, dst, cursor, csrc, NE);

    const int nodeBlocks = (NN + 3) / 4;
    const dim3 splitG(768, 1, 3);
    const int gN = (NN + 63) / 64;    // n-split grid (64 rows/block)
    const int gM = (NN + 255) / 256;  // m-split grid (256 rows/block)

    // ---- layer 0: in=128 (ks=7, cs=2), H=4, F=64, Nc=256 ----
    split3_kernel<<<splitG, 256, 0, stream>>>(feat, A2, NN * 128, 7,
                                              W0, W0s, 256 * 128, 7,
                                              rW0, rW0s, 256 * 128, 7);
    mfma_gemm_dual<<<gN, 256, 0, stream>>>(A2, W0s, rW0s, bufH, bufB, al0, ar0,
                                           el, er, NN, 128, 256, 4, 64, 0, 64, 2);
    gat_agg<4, 64, true><<<nodeBlocks, 256, 0, stream>>>(bufH, el, er, offs, csrc, bufB, NN);

    // ---- layer 1: in=256 (ks=8, cs=3), H=4, F=64, Nc=256 ----
    split3_kernel<<<splitG, 256, 0, stream>>>(bufB, A2, NN * 256, 8,
                                              W1, W1s, 256 * 256, 8,
                                              rW1, rW1s, 256 * 256, 8);
    mfma_gemm_dual<<<gN, 256, 0, stream>>>(A2, W1s, rW1s, bufH, bufC, al1, ar1,
                                           el, er, NN, 256, 256, 4, 64, 0, 64, 3);
    gat_agg<4, 64, true><<<nodeBlocks, 256, 0, stream>>>(bufH, el, er, offs, csrc, bufC, NN);

    // ---- layer 2 (output): in=256 (ks=8, cs=3), H=1, F=40, Nc=40, m-split ----
    split3_kernel<<<splitG, 256, 0, stream>>>(bufC, A2, NN * 256, 8,
                                              W2, W2s, 40 * 256, 8,
                                              rW2, rW2s, 40 * 256, 8);
    mfma_gemm_dual<<<gM, 256, 0, stream>>>(A2, W2s, rW2s, bufH, out, al2, ar2,
                                           el, er, NN, 256, 40, 1, 40, 64, 0, 3);
    gat_agg<1, 40, false><<<nodeBlocks, 256, 0, stream>>>(bufH, el, er, offs, csrc, out, NN);
}

// Round 10
// 681.273 us; speedup vs baseline: 1.4024x; 1.1475x over previous
//
#include <hip/hip_runtime.h>
#include <math.h>

#define NN 50000
#define NE 800000

constexpr float NEG_SLOPE = 0.2f;

typedef float f32x4 __attribute__((ext_vector_type(4)));
typedef float abf  __attribute__((ext_vector_type(4)));  // 4 VGPRs = 8 bf16

// D = A*B + D ; 16x16x32 bf16 MFMA via inline asm (validated rounds 3/7).
__device__ inline void mfma16(f32x4& d, abf a, abf b)
{
    asm("v_mfma_f32_16x16x32_bf16 %0, %1, %2, %0" : "+v"(d) : "v"(a), "v"(b));
}

__device__ inline unsigned short f2bf(float x)
{
    unsigned int u = __float_as_uint(x);
    unsigned int r = (u + 0x7FFFu + ((u >> 16) & 1u)) >> 16;  // RNE
    return (unsigned short)r;
}
__device__ inline float bf2f(unsigned short b)
{
    return __uint_as_float(((unsigned int)b) << 16);
}

// async global -> LDS, 16B per lane (dest = wave-uniform base + lane*16)
__device__ inline void gld16(const void* g, void* l)
{
    __builtin_amdgcn_global_load_lds(
        (const __attribute__((address_space(1))) void*)g,
        (__attribute__((address_space(3))) void*)l, 16, 0, 0);
}

// ---------------------------------------------------------------------------
// split3: three fp32 matrices [M,K] -> bf16 hi|lo [M,2K]. K pow2 (kshift).
// Used only for feat + the 5 weight matrices (activation splits are fused
// into gat_agg's epilogue).
// ---------------------------------------------------------------------------
__global__ __launch_bounds__(256) void split3_kernel(
    const float* __restrict__ X0, unsigned short* __restrict__ Y0, int n0, int ks0,
    const float* __restrict__ X1, unsigned short* __restrict__ Y1, int n1, int ks1,
    const float* __restrict__ X2, unsigned short* __restrict__ Y2, int n2, int ks2)
{
    const int z = blockIdx.z;
    const float* X = (z == 0) ? X0 : (z == 1) ? X1 : X2;
    unsigned short* Y = (z == 0) ? Y0 : (z == 1) ? Y1 : Y2;
    const int n = (z == 0) ? n0 : (z == 1) ? n1 : n2;
    const int ks = (z == 0) ? ks0 : (z == 1) ? ks1 : ks2;
    const int K = 1 << ks;
    const int n4 = n >> 2;
    for (int i = blockIdx.x * blockDim.x + threadIdx.x; i < n4;
         i += gridDim.x * blockDim.x) {
        const float4 v = reinterpret_cast<const float4*>(X)[i];
        const int e0 = i << 2;
        const int m = e0 >> ks;
        const int k = e0 & (K - 1);
        ushort4 hi, lo;
        hi.x = f2bf(v.x); lo.x = f2bf(v.x - bf2f(hi.x));
        hi.y = f2bf(v.y); lo.y = f2bf(v.y - bf2f(hi.y));
        hi.z = f2bf(v.z); lo.z = f2bf(v.z - bf2f(hi.z));
        hi.w = f2bf(v.w); lo.w = f2bf(v.w - bf2f(hi.w));
        *reinterpret_cast<ushort4*>(&Y[(size_t)m * (2 * K) + k]) = hi;
        *reinterpret_cast<ushort4*>(&Y[(size_t)m * (2 * K) + K + k]) = lo;
    }
}

// ---------------------------------------------------------------------------
// LDS-staged MFMA GEMM (m97 structure), split-bf16 over K' = 3K:
//   seg0: Ahi*Bhi  seg1: Alo*Bhi  seg2: Ahi*Blo
// B = concat [B1; B2] rows (W | rW) -> one dispatch per layer.
// Block: 256 thr / 4 waves; tile 128(M) x 128(concat N); BK=64 bf16.
// LDS: A[128][64] + B[128][64] double-buffered = 64 KB; staged via
// global_load_lds x16B; __syncthreads() drains vmcnt (m97 semantics).
// Stores: concat col < NcW -> C1, < 2*NcW -> C2, else skip.
// Fused el/er epilogue from C1 accs (wave's 64 cols == one head).
// ---------------------------------------------------------------------------
__global__ __launch_bounds__(256) void gemm_lds(
    const unsigned short* __restrict__ A2,
    const unsigned short* __restrict__ B1b,
    const unsigned short* __restrict__ B2b,
    float* __restrict__ C1, float* __restrict__ C2,
    const float* __restrict__ al, const float* __restrict__ ar,
    float* __restrict__ el, float* __restrict__ er,
    int M, int K, int NcW, int ldA, int ldB, int ldC1, int ldC2,
    int H, int F, int nsteps)
{
    __shared__ unsigned short As[2][128 * 64];
    __shared__ unsigned short Bs[2][128 * 64];

    const int tid = threadIdx.x;
    const int lane = tid & 63;
    const int w = tid >> 6;
    const int bm = blockIdx.x * 128;
    const int bn = blockIdx.y * 128;

    const int lr = lane & 15;
    const int lkk = (lane >> 4) * 8;
    const int kc8 = (tid & 7) * 8;  // within-row 16B chunk offset (elems)

    // staging descriptors: chunk c = i*256 + tid ; tile row = c>>3
    int a_row[4], b_row[4];
    const unsigned short* b_ptr[4];
#pragma unroll
    for (int i = 0; i < 4; ++i) {
        const int c = i * 256 + tid;
        const int m = c >> 3;
        a_row[i] = min(bm + m, M - 1);
        const int cr = bn + m;
        if (cr < NcW) { b_ptr[i] = B1b; b_row[i] = cr; }
        else if (cr < 2 * NcW) { b_ptr[i] = B2b; b_row[i] = cr - NcW; }
        else { b_ptr[i] = B2b; b_row[i] = NcW - 1; }  // padded cols, never stored
    }

    f32x4 acc[4][4];
#pragma unroll
    for (int mi = 0; mi < 4; ++mi)
#pragma unroll
        for (int ni = 0; ni < 4; ++ni) acc[mi][ni] = (f32x4){0.f, 0.f, 0.f, 0.f};

    auto STAGE = [&](int buf, int t) {
        const int kp = t * 64;
        const int seg = (kp >= 2 * K) ? 2 : ((kp >= K) ? 1 : 0);
        const int kk0 = kp - seg * K;
        const int acol = kk0 + ((seg == 1) ? K : 0) + kc8;
        const int bcol = kk0 + ((seg == 2) ? K : 0) + kc8;
        unsigned short* ab = &As[buf][0];
        unsigned short* bb = &Bs[buf][0];
#pragma unroll
        for (int i = 0; i < 4; ++i) {
            const int c = i * 256 + tid;
            gld16(&A2[(size_t)a_row[i] * ldA + acol], ab + (size_t)c * 8);
            gld16(&b_ptr[i][(size_t)b_row[i] * ldB + bcol], bb + (size_t)c * 8);
        }
    };

    STAGE(0, 0);
    __syncthreads();  // drains vmcnt(0) before barrier (HIP semantics)

    const int m0l = (w >> 1) * 64;  // wave-local row base
    const int n0l = (w & 1) * 64;   // wave-local concat-col base

    int cur = 0;
    for (int t = 0; t < nsteps; ++t) {
        if (t + 1 < nsteps) STAGE(cur ^ 1, t + 1);
#pragma unroll
        for (int kk = 0; kk < 64; kk += 32) {
            abf a[4], b[4];
#pragma unroll
            for (int mi = 0; mi < 4; ++mi)
                a[mi] = *reinterpret_cast<const abf*>(
                    &As[cur][(m0l + mi * 16 + lr) * 64 + kk + lkk]);
#pragma unroll
            for (int ni = 0; ni < 4; ++ni)
                b[ni] = *reinterpret_cast<const abf*>(
                    &Bs[cur][(n0l + ni * 16 + lr) * 64 + kk + lkk]);
#pragma unroll
            for (int mi = 0; mi < 4; ++mi)
#pragma unroll
                for (int ni = 0; ni < 4; ++ni) mfma16(acc[mi][ni], a[mi], b[ni]);
        }
        __syncthreads();  // all reads of cur done; next-tile stage drained
        cur ^= 1;
    }

    // MFMA (inline asm, opaque to hazard recognizer) -> VALU read guard.
    __builtin_amdgcn_sched_barrier(0);
    asm volatile("s_nop 7\n\ts_nop 7");
    __builtin_amdgcn_sched_barrier(0);

    // ---- store C1/C2 ----  lane holds C[row=(lane>>4)*4+r][col=lane&15]
#pragma unroll
    for (int mi = 0; mi < 4; ++mi) {
#pragma unroll
        for (int ni = 0; ni < 4; ++ni) {
            const int gc = bn + n0l + ni * 16 + lr;
            float* Cp = nullptr;
            int cc = 0, ldc = 0;
            if (gc < NcW) { Cp = C1; cc = gc; ldc = ldC1; }
            else if (gc < 2 * NcW) { Cp = C2; cc = gc - NcW; ldc = ldC2; }
            if (Cp != nullptr) {
#pragma unroll
                for (int r = 0; r < 4; ++r) {
                    const int row = bm + m0l + mi * 16 + (lane >> 4) * 4 + r;
                    if (row < M) Cp[(size_t)row * ldc + cc] = acc[mi][ni][r];
                }
            }
        }
    }

    // ---- fused el/er epilogue (W region only; wave's 64 cols == one head) ----
    const int n0g = bn + n0l;
    if (el != nullptr && n0g < NcW) {
        const int head = n0g >> 6;
        float alv[4], arv[4];
#pragma unroll
        for (int ni = 0; ni < 4; ++ni) {
            const int f = ni * 16 + lr;
            alv[ni] = (f < F) ? al[head * F + f] : 0.f;
            arv[ni] = (f < F) ? ar[head * F + f] : 0.f;
        }
#pragma unroll
        for (int mi = 0; mi < 4; ++mi) {
#pragma unroll
            for (int r = 0; r < 4; ++r) {
                float dl = 0.f, dr = 0.f;
#pragma unroll
                for (int ni = 0; ni < 4; ++ni) {
                    dl += acc[mi][ni][r] * alv[ni];
                    dr += acc[mi][ni][r] * arv[ni];
                }
#pragma unroll
                for (int o = 1; o < 16; o <<= 1) {
                    dl += __shfl_xor(dl, o);
                    dr += __shfl_xor(dr, o);
                }
                const int row = bm + m0l + mi * 16 + (lane >> 4) * 4 + r;
                if (lr == 0 && row < M) {
                    el[(size_t)row * H + head] = dl;
                    er[(size_t)row * H + head] = dr;
                }
            }
        }
    }
}

// ---------------------------------------------------------------------------
// CSR build: histogram -> hierarchical scan -> scatter
// ---------------------------------------------------------------------------
__global__ void hist_kernel(const int* __restrict__ dst, int* __restrict__ deg, int E)
{
    const int i = blockIdx.x * blockDim.x + threadIdx.x;
    if (i < E) atomicAdd(&deg[dst[i]], 1);
}

__global__ __launch_bounds__(1024) void scan_part(const int* __restrict__ deg,
                                                  int* __restrict__ psum, int N)
{
    __shared__ int wsum[16];
    const int i = blockIdx.x * 1024 + threadIdx.x;
    const int lane = threadIdx.x & 63;
    const int wv = threadIdx.x >> 6;
    int s = (i < N) ? deg[i] : 0;
#pragma unroll
    for (int o = 1; o < 64; o <<= 1) s += __shfl_xor(s, o);
    if (lane == 0) wsum[wv] = s;
    __syncthreads();
    if (threadIdx.x == 0) {
        int t = 0;
#pragma unroll
        for (int k = 0; k < 16; ++k) t += wsum[k];
        psum[blockIdx.x] = t;
    }
}

__global__ void scan_tops(int* __restrict__ psum, int* __restrict__ offs, int nb, int N)
{
    const int lane = threadIdx.x;  // 64 threads, nb <= 64
    const int v = (lane < nb) ? psum[lane] : 0;
    int x = v;
#pragma unroll
    for (int o = 1; o < 64; o <<= 1) {
        const int t = __shfl_up(x, o);
        if (lane >= o) x += t;
    }
    if (lane < nb) psum[lane] = x - v;  // exclusive
    if (lane == nb - 1) offs[N] = x;    // grand total
}

__global__ __launch_bounds__(1024) void scan_final(const int* __restrict__ deg,
                                                   const int* __restrict__ psum,
                                                   int* __restrict__ offs,
                                                   int* __restrict__ cursor, int N)
{
    __shared__ int wsums[16];
    const int i = blockIdx.x * 1024 + threadIdx.x;
    const int lane = threadIdx.x & 63;
    const int wv = threadIdx.x >> 6;
    const int v = (i < N) ? deg[i] : 0;
    int x = v;
#pragma unroll
    for (int o = 1; o < 64; o <<= 1) {
        const int t = __shfl_up(x, o);
        if (lane >= o) x += t;
    }
    if (lane == 63) wsums[wv] = x;
    __syncthreads();
    if (wv == 0) {
        int wsv = (lane < 16) ? wsums[lane] : 0;
#pragma unroll
        for (int o = 1; o < 16; o <<= 1) {
            const int t = __shfl_up(wsv, o);
            if (lane >= o) wsv += t;
        }
        if (lane < 16) wsums[lane] = wsv;
    }
    __syncthreads();
    const int wexcl = (wv == 0) ? 0 : wsums[wv - 1];
    const int excl = psum[blockIdx.x] + wexcl + (x - v);
    if (i < N) { offs[i] = excl; cursor[i] = excl; }
}

__global__ void scatter_kernel(const int* __restrict__ src, const int* __restrict__ dst,
                               int* __restrict__ cursor, int* __restrict__ csrc, int E)
{
    const int i = blockIdx.x * blockDim.x + threadIdx.x;
    if (i < E) {
        const int d = dst[i];
        const int pos = atomicAdd(&cursor[d], 1);
        csrc[pos] = src[i];
    }
}

// ---------------------------------------------------------------------------
// GAT aggregation, online-softmax single pass. Wave per destination node.
// SPLIT: write result as bf16 hi|lo (next layer's GEMM A input, stride 2*HF)
// instead of fp32 — bit-identical to split3(fp32 result).
// ---------------------------------------------------------------------------
template <int H, int F, bool DO_ELU, bool SPLIT>
__global__ __launch_bounds__(256) void gat_agg(const float* __restrict__ Hb,
                                               const float* __restrict__ el,
                                               const float* __restrict__ er,
                                               const int* __restrict__ offs,
                                               const int* __restrict__ csrc,
                                               const float* __restrict__ Res,
                                               float* __restrict__ outF,
                                               unsigned short* __restrict__ outB,
                                               int N)
{
    constexpr int HF = H * F;
    constexpr int CS = 64 / H;
    constexpr bool VEC4 = (HF == 256);
    const int node = blockIdx.x * 4 + (threadIdx.x >> 6);
    const int lane = threadIdx.x & 63;
    if (node >= N) return;
    // clamped (robust against profiler replay with stale ws)
    int off = offs[node], end = offs[node + 1];
    off = max(0, min(off, NE));
    end = max(off, min(end, NE));
    const int deg = end - off;
    const int edge_sl = lane & (CS - 1);
    const int head = lane / CS;
    const int gbase = lane & ~(CS - 1);

    const float erh = er[(size_t)node * H + head];

    float m = -INFINITY;
    float dsum = 0.f;
    float acc0 = 0.f, acc1 = 0.f, acc2 = 0.f, acc3 = 0.f;

    for (int base = 0; base < deg; base += CS) {
        const int cnt = min(CS, deg - base);
        int s_reg = 0;
        float sv = -INFINITY;
        if (edge_sl < cnt) {
            s_reg = min(max(csrc[off + base + edge_sl], 0), N - 1);
            const float x = el[(size_t)s_reg * H + head] + erh;
            sv = (x >= 0.f) ? x : NEG_SLOPE * x;
        }
        float cm = sv;
#pragma unroll
        for (int o = 1; o < CS; o <<= 1) cm = fmaxf(cm, __shfl_xor(cm, o));
        const float mn = fmaxf(m, cm);
        const float sc = __expf(m - mn);  // first chunk: exp(-inf)=0
        dsum *= sc; acc0 *= sc; acc1 *= sc; acc2 *= sc; acc3 *= sc;
        m = mn;
        const float p = (edge_sl < cnt) ? __expf(sv - mn) : 0.f;
        dsum += p;

        int e = 0;
        for (; e + 1 < cnt; e += 2) {
            const float pe0 = __shfl(p, gbase + e);
            const int se0 = __shfl(s_reg, gbase + e);
            const float pe1 = __shfl(p, gbase + e + 1);
            const int se1 = __shfl(s_reg, gbase + e + 1);
            if (VEC4) {
                const float4 h0 =
                    *reinterpret_cast<const float4*>(&Hb[(size_t)se0 * HF + lane * 4]);
                const float4 h1 =
                    *reinterpret_cast<const float4*>(&Hb[(size_t)se1 * HF + lane * 4]);
                acc0 += pe0 * h0.x; acc1 += pe0 * h0.y;
                acc2 += pe0 * h0.z; acc3 += pe0 * h0.w;
                acc0 += pe1 * h1.x; acc1 += pe1 * h1.y;
                acc2 += pe1 * h1.z; acc3 += pe1 * h1.w;
            } else if (lane < HF) {
                const float v0 = Hb[(size_t)se0 * HF + lane];
                const float v1 = Hb[(size_t)se1 * HF + lane];
                acc0 += pe0 * v0 + pe1 * v1;
            }
        }
        if (e < cnt) {
            const float pe = __shfl(p, gbase + e);
            const int se = __shfl(s_reg, gbase + e);
            if (VEC4) {
                const float4 hv =
                    *reinterpret_cast<const float4*>(&Hb[(size_t)se * HF + lane * 4]);
                acc0 += pe * hv.x; acc1 += pe * hv.y;
                acc2 += pe * hv.z; acc3 += pe * hv.w;
            } else if (lane < HF) {
                acc0 += pe * Hb[(size_t)se * HF + lane];
            }
        }
    }

#pragma unroll
    for (int o = 1; o < CS; o <<= 1) dsum += __shfl_xor(dsum, o);
    const float inv = (dsum > 0.f) ? 1.f / dsum : 0.f;

    if (VEC4) {
        const float4 rr =
            *reinterpret_cast<const float4*>(&Res[(size_t)node * HF + lane * 4]);
        float o0 = acc0 * inv + rr.x;
        float o1 = acc1 * inv + rr.y;
        float o2 = acc2 * inv + rr.z;
        float o3 = acc3 * inv + rr.w;
        if (DO_ELU) {
            o0 = (o0 > 0.f) ? o0 : expm1f(o0);
            o1 = (o1 > 0.f) ? o1 : expm1f(o1);
            o2 = (o2 > 0.f) ? o2 : expm1f(o2);
            o3 = (o3 > 0.f) ? o3 : expm1f(o3);
        }
        if (SPLIT) {
            ushort4 hi, lo;
            hi.x = f2bf(o0); lo.x = f2bf(o0 - bf2f(hi.x));
            hi.y = f2bf(o1); lo.y = f2bf(o1 - bf2f(hi.y));
            hi.z = f2bf(o2); lo.z = f2bf(o2 - bf2f(hi.z));
            hi.w = f2bf(o3); lo.w = f2bf(o3 - bf2f(hi.w));
            *reinterpret_cast<ushort4*>(&outB[(size_t)node * (2 * HF) + lane * 4]) = hi;
            *reinterpret_cast<ushort4*>(&outB[(size_t)node * (2 * HF) + HF + lane * 4]) = lo;
        } else {
            *reinterpret_cast<float4*>(&outF[(size_t)node * HF + lane * 4]) =
                make_float4(o0, o1, o2, o3);
        }
    } else if (lane < HF) {
        float o = acc0 * inv + Res[(size_t)node * HF + lane];
        if (DO_ELU) o = (o > 0.f) ? o : expm1f(o);
        outF[(size_t)node * HF + lane] = o;
    }
}

// ---------------------------------------------------------------------------
extern "C" void kernel_launch(void* const* d_in, const int* in_sizes, int n_in,
                              void* d_out, int out_size, void* d_ws, size_t ws_size,
                              hipStream_t stream)
{
    const float* feat = (const float*)d_in[0];
    const int* src = (const int*)d_in[1];
    const int* dst = (const int*)d_in[2];
    const float* W0 = (const float*)d_in[3];
    const float* al0 = (const float*)d_in[4];
    const float* ar0 = (const float*)d_in[5];
    const float* rW0 = (const float*)d_in[6];
    const float* W1 = (const float*)d_in[7];
    const float* al1 = (const float*)d_in[8];
    const float* ar1 = (const float*)d_in[9];
    const float* rW1 = (const float*)d_in[10];
    const float* W2 = (const float*)d_in[11];
    const float* al2 = (const float*)d_in[12];
    const float* ar2 = (const float*)d_in[13];
    const float* rW2 = (const float*)d_in[14];
    float* out = (float*)d_out;

    char* ws = (char*)d_ws;
    size_t o = 0;
    auto alloc = [&](size_t bytes) -> void* {
        void* p = ws + o;
        o += (bytes + 255) & ~(size_t)255;
        return p;
    };
    unsigned short* A2 = (unsigned short*)alloc((size_t)NN * 512 * 2);  // hi|lo acts
    float* bufH = (float*)alloc((size_t)NN * 256 * 4);                  // h
    float* bufR = (float*)alloc((size_t)NN * 256 * 4);                  // residual
    unsigned short* W0s = (unsigned short*)alloc((size_t)256 * 256 * 2);
    unsigned short* rW0s = (unsigned short*)alloc((size_t)256 * 256 * 2);
    unsigned short* W1s = (unsigned short*)alloc((size_t)256 * 512 * 2);
    unsigned short* rW1s = (unsigned short*)alloc((size_t)256 * 512 * 2);
    unsigned short* W2s = (unsigned short*)alloc((size_t)40 * 512 * 2);
    unsigned short* rW2s = (unsigned short*)alloc((size_t)40 * 512 * 2);
    float* el = (float*)alloc((size_t)NN * 4 * 4);
    float* er = (float*)alloc((size_t)NN * 4 * 4);
    int* deg = (int*)alloc((size_t)NN * 4);
    int* offs = (int*)alloc((size_t)(NN + 1) * 4);
    int* cursor = (int*)alloc((size_t)NN * 4);
    int* psum = (int*)alloc((size_t)64 * 4);
    int* csrc = (int*)alloc((size_t)NE * 4);

    // ---- all splits upfront (feat + weights; activations fused into agg) ----
    const dim3 splitG(768, 1, 3);
    split3_kernel<<<splitG, 256, 0, stream>>>(feat, A2, NN * 128, 7,
                                              W0, W0s, 256 * 128, 7,
                                              rW0, rW0s, 256 * 128, 7);
    split3_kernel<<<splitG, 256, 0, stream>>>(W1, W1s, 256 * 256, 8,
                                              rW1, rW1s, 256 * 256, 8,
                                              W2, W2s, 40 * 256, 8);
    split3_kernel<<<splitG, 256, 0, stream>>>(rW2, rW2s, 40 * 256, 8,
                                              rW2, rW2s, 0, 8,
                                              rW2, rW2s, 0, 8);

    // ---- CSR build (by dst), shared across all 3 layers ----
    const int nb = (NN + 1023) / 1024;  // 49
    hipMemsetAsync(deg, 0, NN * sizeof(int), stream);
    hist_kernel<<<(NE + 255) / 256, 256, 0, stream>>>(dst, deg, NE);
    scan_part<<<nb, 1024, 0, stream>>>(deg, psum, NN);
    scan_tops<<<1, 64, 0, stream>>>(psum, offs, nb, NN);
    scan_final<<<nb, 1024, 0, stream>>>(deg, psum, offs, cursor, NN);
    scatter_kernel<<<(NE + 255) / 256, 256, 0, stream>>>(src, dst, cursor, csrc, NE);

    const int nodeBlocks = (NN + 3) / 4;
    const int gx = (NN + 127) / 128;  // 391

    // ---- layer 0: K=128 (K'=384, 6 steps), NcW=256, H=4, F=64 ----
    {
        dim3 g(gx, 4);
        gemm_lds<<<g, 256, 0, stream>>>(A2, W0s, rW0s, bufH, bufR, al0, ar0, el, er,
                                        NN, 128, 256, 256, 256, 256, 256, 4, 64, 6);
        gat_agg<4, 64, true, true><<<nodeBlocks, 256, 0, stream>>>(
            bufH, el, er, offs, csrc, bufR, nullptr, A2, NN);
    }
    // ---- layer 1: K=256 (K'=768, 12 steps), NcW=256, H=4, F=64 ----
    {
        dim3 g(gx, 4);
        gemm_lds<<<g, 256, 0, stream>>>(A2, W1s, rW1s, bufH, bufR, al1, ar1, el, er,
                                        NN, 256, 256, 512, 512, 256, 256, 4, 64, 12);
        gat_agg<4, 64, true, true><<<nodeBlocks, 256, 0, stream>>>(
            bufH, el, er, offs, csrc, bufR, nullptr, A2, NN);
    }
    // ---- layer 2: K=256 (K'=768, 12 steps), NcW=40, H=1, F=40 ----
    {
        dim3 g(gx, 1);
        gemm_lds<<<g, 256, 0, stream>>>(A2, W2s, rW2s, bufH, out, al2, ar2, el, er,
                                        NN, 256, 40, 512, 512, 40, 40, 1, 40, 12);
        gat_agg<1, 40, false, false><<<nodeBlocks, 256, 0, stream>>>(
            bufH, el, er, offs, csrc, out, out, nullptr, NN);
    }
}

// Round 11
// 549.803 us; speedup vs baseline: 1.7378x; 1.2391x over previous
//
#include <hip/hip_runtime.h>
#include <math.h>

#define NN 50000
#define NE 800000

constexpr float NEG_SLOPE = 0.2f;

typedef float f32x4 __attribute__((ext_vector_type(4)));
typedef float abf  __attribute__((ext_vector_type(4)));  // 4 VGPRs = 8 bf16

// D = A*B + D ; 16x16x32 bf16 MFMA via inline asm (validated rounds 3/7/10).
__device__ inline void mfma16(f32x4& d, abf a, abf b)
{
    asm("v_mfma_f32_16x16x32_bf16 %0, %1, %2, %0" : "+v"(d) : "v"(a), "v"(b));
}

__device__ inline unsigned short f2bf(float x)
{
    unsigned int u = __float_as_uint(x);
    unsigned int r = (u + 0x7FFFu + ((u >> 16) & 1u)) >> 16;  // RNE
    return (unsigned short)r;
}
__device__ inline float bf2f(unsigned short b)
{
    return __uint_as_float(((unsigned int)b) << 16);
}

// async global -> LDS, 16B per lane (dest = wave-uniform base + lane*16)
__device__ inline void gld16(const void* g, void* l)
{
    __builtin_amdgcn_global_load_lds(
        (const __attribute__((address_space(1))) void*)g,
        (__attribute__((address_space(3))) void*)l, 16, 0, 0);
}

// ---------------------------------------------------------------------------
// split3: three fp32 matrices [M,K] -> bf16 hi|lo [M,2K]. K pow2 (kshift).
// ---------------------------------------------------------------------------
__global__ __launch_bounds__(256) void split3_kernel(
    const float* __restrict__ X0, unsigned short* __restrict__ Y0, int n0, int ks0,
    const float* __restrict__ X1, unsigned short* __restrict__ Y1, int n1, int ks1,
    const float* __restrict__ X2, unsigned short* __restrict__ Y2, int n2, int ks2)
{
    const int z = blockIdx.z;
    const float* X = (z == 0) ? X0 : (z == 1) ? X1 : X2;
    unsigned short* Y = (z == 0) ? Y0 : (z == 1) ? Y1 : Y2;
    const int n = (z == 0) ? n0 : (z == 1) ? n1 : n2;
    const int ks = (z == 0) ? ks0 : (z == 1) ? ks1 : ks2;
    const int K = 1 << ks;
    const int n4 = n >> 2;
    for (int i = blockIdx.x * blockDim.x + threadIdx.x; i < n4;
         i += gridDim.x * blockDim.x) {
        const float4 v = reinterpret_cast<const float4*>(X)[i];
        const int e0 = i << 2;
        const int m = e0 >> ks;
        const int k = e0 & (K - 1);
        ushort4 hi, lo;
        hi.x = f2bf(v.x); lo.x = f2bf(v.x - bf2f(hi.x));
        hi.y = f2bf(v.y); lo.y = f2bf(v.y - bf2f(hi.y));
        hi.z = f2bf(v.z); lo.z = f2bf(v.z - bf2f(hi.z));
        hi.w = f2bf(v.w); lo.w = f2bf(v.w - bf2f(hi.w));
        *reinterpret_cast<ushort4*>(&Y[(size_t)m * (2 * K) + k]) = hi;
        *reinterpret_cast<ushort4*>(&Y[(size_t)m * (2 * K) + K + k]) = lo;
    }
}

// ---------------------------------------------------------------------------
// LDS-staged MFMA GEMM (m97 structure), split-bf16 over K' = 3K.
// C1 (h, consumed only by the agg gather) is stored as BF16 [M,ldC1];
// C2 (residual) stays fp32. el/er epilogue uses full-precision accs.
// ---------------------------------------------------------------------------
__global__ __launch_bounds__(256) void gemm_lds(
    const unsigned short* __restrict__ A2,
    const unsigned short* __restrict__ B1b,
    const unsigned short* __restrict__ B2b,
    unsigned short* __restrict__ C1, float* __restrict__ C2,
    const float* __restrict__ al, const float* __restrict__ ar,
    float* __restrict__ el, float* __restrict__ er,
    int M, int K, int NcW, int ldA, int ldB, int ldC1, int ldC2,
    int H, int F, int nsteps)
{
    __shared__ unsigned short As[2][128 * 64];
    __shared__ unsigned short Bs[2][128 * 64];

    const int tid = threadIdx.x;
    const int lane = tid & 63;
    const int w = tid >> 6;
    const int bm = blockIdx.x * 128;
    const int bn = blockIdx.y * 128;

    const int lr = lane & 15;
    const int lkk = (lane >> 4) * 8;
    const int kc8 = (tid & 7) * 8;  // within-row 16B chunk offset (elems)

    // staging descriptors: chunk c = i*256 + tid ; tile row = c>>3
    int a_row[4], b_row[4];
    const unsigned short* b_ptr[4];
#pragma unroll
    for (int i = 0; i < 4; ++i) {
        const int c = i * 256 + tid;
        const int m = c >> 3;
        a_row[i] = min(bm + m, M - 1);
        const int cr = bn + m;
        if (cr < NcW) { b_ptr[i] = B1b; b_row[i] = cr; }
        else if (cr < 2 * NcW) { b_ptr[i] = B2b; b_row[i] = cr - NcW; }
        else { b_ptr[i] = B2b; b_row[i] = NcW - 1; }  // padded cols, never stored
    }

    f32x4 acc[4][4];
#pragma unroll
    for (int mi = 0; mi < 4; ++mi)
#pragma unroll
        for (int ni = 0; ni < 4; ++ni) acc[mi][ni] = (f32x4){0.f, 0.f, 0.f, 0.f};

    auto STAGE = [&](int buf, int t) {
        const int kp = t * 64;
        const int seg = (kp >= 2 * K) ? 2 : ((kp >= K) ? 1 : 0);
        const int kk0 = kp - seg * K;
        const int acol = kk0 + ((seg == 1) ? K : 0) + kc8;
        const int bcol = kk0 + ((seg == 2) ? K : 0) + kc8;
        unsigned short* ab = &As[buf][0];
        unsigned short* bb = &Bs[buf][0];
#pragma unroll
        for (int i = 0; i < 4; ++i) {
            const int c = i * 256 + tid;
            gld16(&A2[(size_t)a_row[i] * ldA + acol], ab + (size_t)c * 8);
            gld16(&b_ptr[i][(size_t)b_row[i] * ldB + bcol], bb + (size_t)c * 8);
        }
    };

    STAGE(0, 0);
    __syncthreads();  // drains vmcnt(0) before barrier (HIP semantics)

    const int m0l = (w >> 1) * 64;  // wave-local row base
    const int n0l = (w & 1) * 64;   // wave-local concat-col base

    int cur = 0;
    for (int t = 0; t < nsteps; ++t) {
        if (t + 1 < nsteps) STAGE(cur ^ 1, t + 1);
#pragma unroll
        for (int kk = 0; kk < 64; kk += 32) {
            abf a[4], b[4];
#pragma unroll
            for (int mi = 0; mi < 4; ++mi)
                a[mi] = *reinterpret_cast<const abf*>(
                    &As[cur][(m0l + mi * 16 + lr) * 64 + kk + lkk]);
#pragma unroll
            for (int ni = 0; ni < 4; ++ni)
                b[ni] = *reinterpret_cast<const abf*>(
                    &Bs[cur][(n0l + ni * 16 + lr) * 64 + kk + lkk]);
#pragma unroll
            for (int mi = 0; mi < 4; ++mi)
#pragma unroll
                for (int ni = 0; ni < 4; ++ni) mfma16(acc[mi][ni], a[mi], b[ni]);
        }
        __syncthreads();  // all reads of cur done; next-tile stage drained
        cur ^= 1;
    }

    // MFMA (inline asm, opaque to hazard recognizer) -> VALU read guard.
    __builtin_amdgcn_sched_barrier(0);
    asm volatile("s_nop 7\n\ts_nop 7");
    __builtin_amdgcn_sched_barrier(0);

    // ---- store C1 (bf16) / C2 (fp32) ----
#pragma unroll
    for (int mi = 0; mi < 4; ++mi) {
#pragma unroll
        for (int ni = 0; ni < 4; ++ni) {
            const int gc = bn + n0l + ni * 16 + lr;
            if (gc < NcW) {
#pragma unroll
                for (int r = 0; r < 4; ++r) {
                    const int row = bm + m0l + mi * 16 + (lane >> 4) * 4 + r;
                    if (row < M) C1[(size_t)row * ldC1 + gc] = f2bf(acc[mi][ni][r]);
                }
            } else if (gc < 2 * NcW) {
                const int cc = gc - NcW;
#pragma unroll
                for (int r = 0; r < 4; ++r) {
                    const int row = bm + m0l + mi * 16 + (lane >> 4) * 4 + r;
                    if (row < M) C2[(size_t)row * ldC2 + cc] = acc[mi][ni][r];
                }
            }
        }
    }

    // ---- fused el/er epilogue (W region only; wave's 64 cols == one head) ----
    const int n0g = bn + n0l;
    if (el != nullptr && n0g < NcW) {
        const int head = n0g >> 6;
        float alv[4], arv[4];
#pragma unroll
        for (int ni = 0; ni < 4; ++ni) {
            const int f = ni * 16 + lr;
            alv[ni] = (f < F) ? al[head * F + f] : 0.f;
            arv[ni] = (f < F) ? ar[head * F + f] : 0.f;
        }
#pragma unroll
        for (int mi = 0; mi < 4; ++mi) {
#pragma unroll
            for (int r = 0; r < 4; ++r) {
                float dl = 0.f, dr = 0.f;
#pragma unroll
                for (int ni = 0; ni < 4; ++ni) {
                    dl += acc[mi][ni][r] * alv[ni];
                    dr += acc[mi][ni][r] * arv[ni];
                }
#pragma unroll
                for (int o = 1; o < 16; o <<= 1) {
                    dl += __shfl_xor(dl, o);
                    dr += __shfl_xor(dr, o);
                }
                const int row = bm + m0l + mi * 16 + (lane >> 4) * 4 + r;
                if (lr == 0 && row < M) {
                    el[(size_t)row * H + head] = dl;
                    er[(size_t)row * H + head] = dr;
                }
            }
        }
    }
}

// ---------------------------------------------------------------------------
// CSR build: histogram -> hierarchical scan -> scatter
// ---------------------------------------------------------------------------
__global__ void hist_kernel(const int* __restrict__ dst, int* __restrict__ deg, int E)
{
    const int i = blockIdx.x * blockDim.x + threadIdx.x;
    if (i < E) atomicAdd(&deg[dst[i]], 1);
}

__global__ __launch_bounds__(1024) void scan_part(const int* __restrict__ deg,
                                                  int* __restrict__ psum, int N)
{
    __shared__ int wsum[16];
    const int i = blockIdx.x * 1024 + threadIdx.x;
    const int lane = threadIdx.x & 63;
    const int wv = threadIdx.x >> 6;
    int s = (i < N) ? deg[i] : 0;
#pragma unroll
    for (int o = 1; o < 64; o <<= 1) s += __shfl_xor(s, o);
    if (lane == 0) wsum[wv] = s;
    __syncthreads();
    if (threadIdx.x == 0) {
        int t = 0;
#pragma unroll
        for (int k = 0; k < 16; ++k) t += wsum[k];
        psum[blockIdx.x] = t;
    }
}

__global__ void scan_tops(int* __restrict__ psum, int* __restrict__ offs, int nb, int N)
{
    const int lane = threadIdx.x;  // 64 threads, nb <= 64
    const int v = (lane < nb) ? psum[lane] : 0;
    int x = v;
#pragma unroll
    for (int o = 1; o < 64; o <<= 1) {
        const int t = __shfl_up(x, o);
        if (lane >= o) x += t;
    }
    if (lane < nb) psum[lane] = x - v;  // exclusive
    if (lane == nb - 1) offs[N] = x;    // grand total
}

__global__ __launch_bounds__(1024) void scan_final(const int* __restrict__ deg,
                                                   const int* __restrict__ psum,
                                                   int* __restrict__ offs,
                                                   int* __restrict__ cursor, int N)
{
    __shared__ int wsums[16];
    const int i = blockIdx.x * 1024 + threadIdx.x;
    const int lane = threadIdx.x & 63;
    const int wv = threadIdx.x >> 6;
    const int v = (i < N) ? deg[i] : 0;
    int x = v;
#pragma unroll
    for (int o = 1; o < 64; o <<= 1) {
        const int t = __shfl_up(x, o);
        if (lane >= o) x += t;
    }
    if (lane == 63) wsums[wv] = x;
    __syncthreads();
    if (wv == 0) {
        int wsv = (lane < 16) ? wsums[lane] : 0;
#pragma unroll
        for (int o = 1; o < 16; o <<= 1) {
            const int t = __shfl_up(wsv, o);
            if (lane >= o) wsv += t;
        }
        if (lane < 16) wsums[lane] = wsv;
    }
    __syncthreads();
    const int wexcl = (wv == 0) ? 0 : wsums[wv - 1];
    const int excl = psum[blockIdx.x] + wexcl + (x - v);
    if (i < N) { offs[i] = excl; cursor[i] = excl; }
}

__global__ void scatter_kernel(const int* __restrict__ src, const int* __restrict__ dst,
                               int* __restrict__ cursor, int* __restrict__ csrc, int E)
{
    const int i = blockIdx.x * blockDim.x + threadIdx.x;
    if (i < E) {
        const int d = dst[i];
        const int pos = atomicAdd(&cursor[d], 1);
        csrc[pos] = src[i];
    }
}

// ---------------------------------------------------------------------------
// GAT aggregation, online-softmax single pass. Wave per destination node.
// Hb is BF16 (half the gather bytes of fp32; L2-resident working set).
// SPLIT: write result as bf16 hi|lo (next layer's GEMM A input, stride 2*HF).
// ---------------------------------------------------------------------------
template <int H, int F, bool DO_ELU, bool SPLIT>
__global__ __launch_bounds__(256) void gat_agg(const unsigned short* __restrict__ Hb,
                                               const float* __restrict__ el,
                                               const float* __restrict__ er,
                                               const int* __restrict__ offs,
                                               const int* __restrict__ csrc,
                                               const float* __restrict__ Res,
                                               float* __restrict__ outF,
                                               unsigned short* __restrict__ outB,
                                               int N)
{
    constexpr int HF = H * F;
    constexpr int CS = 64 / H;
    constexpr bool VEC4 = (HF == 256);
    const int node = blockIdx.x * 4 + (threadIdx.x >> 6);
    const int lane = threadIdx.x & 63;
    if (node >= N) return;
    // clamped (robust against profiler replay with stale ws)
    int off = offs[node], end = offs[node + 1];
    off = max(0, min(off, NE));
    end = max(off, min(end, NE));
    const int deg = end - off;
    const int edge_sl = lane & (CS - 1);
    const int head = lane / CS;
    const int gbase = lane & ~(CS - 1);

    const float erh = er[(size_t)node * H + head];

    float m = -INFINITY;
    float dsum = 0.f;
    float acc0 = 0.f, acc1 = 0.f, acc2 = 0.f, acc3 = 0.f;

    for (int base = 0; base < deg; base += CS) {
        const int cnt = min(CS, deg - base);
        int s_reg = 0;
        float sv = -INFINITY;
        if (edge_sl < cnt) {
            s_reg = min(max(csrc[off + base + edge_sl], 0), N - 1);
            const float x = el[(size_t)s_reg * H + head] + erh;
            sv = (x >= 0.f) ? x : NEG_SLOPE * x;
        }
        float cm = sv;
#pragma unroll
        for (int o = 1; o < CS; o <<= 1) cm = fmaxf(cm, __shfl_xor(cm, o));
        const float mn = fmaxf(m, cm);
        const float sc = __expf(m - mn);  // first chunk: exp(-inf)=0
        dsum *= sc; acc0 *= sc; acc1 *= sc; acc2 *= sc; acc3 *= sc;
        m = mn;
        const float p = (edge_sl < cnt) ? __expf(sv - mn) : 0.f;
        dsum += p;

        int e = 0;
        for (; e + 1 < cnt; e += 2) {
            const float pe0 = __shfl(p, gbase + e);
            const int se0 = __shfl(s_reg, gbase + e);
            const float pe1 = __shfl(p, gbase + e + 1);
            const int se1 = __shfl(s_reg, gbase + e + 1);
            if (VEC4) {
                const ushort4 h0 =
                    *reinterpret_cast<const ushort4*>(&Hb[(size_t)se0 * HF + lane * 4]);
                const ushort4 h1 =
                    *reinterpret_cast<const ushort4*>(&Hb[(size_t)se1 * HF + lane * 4]);
                acc0 += pe0 * bf2f(h0.x); acc1 += pe0 * bf2f(h0.y);
                acc2 += pe0 * bf2f(h0.z); acc3 += pe0 * bf2f(h0.w);
                acc0 += pe1 * bf2f(h1.x); acc1 += pe1 * bf2f(h1.y);
                acc2 += pe1 * bf2f(h1.z); acc3 += pe1 * bf2f(h1.w);
            } else if (lane < HF) {
                const float v0 = bf2f(Hb[(size_t)se0 * HF + lane]);
                const float v1 = bf2f(Hb[(size_t)se1 * HF + lane]);
                acc0 += pe0 * v0 + pe1 * v1;
            }
        }
        if (e < cnt) {
            const float pe = __shfl(p, gbase + e);
            const int se = __shfl(s_reg, gbase + e);
            if (VEC4) {
                const ushort4 hv =
                    *reinterpret_cast<const ushort4*>(&Hb[(size_t)se * HF + lane * 4]);
                acc0 += pe * bf2f(hv.x); acc1 += pe * bf2f(hv.y);
                acc2 += pe * bf2f(hv.z); acc3 += pe * bf2f(hv.w);
            } else if (lane < HF) {
                acc0 += pe * bf2f(Hb[(size_t)se * HF + lane]);
            }
        }
    }

#pragma unroll
    for (int o = 1; o < CS; o <<= 1) dsum += __shfl_xor(dsum, o);
    const float inv = (dsum > 0.f) ? 1.f / dsum : 0.f;

    if (VEC4) {
        const float4 rr =
            *reinterpret_cast<const float4*>(&Res[(size_t)node * HF + lane * 4]);
        float o0 = acc0 * inv + rr.x;
        float o1 = acc1 * inv + rr.y;
        float o2 = acc2 * inv + rr.z;
        float o3 = acc3 * inv + rr.w;
        if (DO_ELU) {
            o0 = (o0 > 0.f) ? o0 : expm1f(o0);
            o1 = (o1 > 0.f) ? o1 : expm1f(o1);
            o2 = (o2 > 0.f) ? o2 : expm1f(o2);
            o3 = (o3 > 0.f) ? o3 : expm1f(o3);
        }
        if (SPLIT) {
            ushort4 hi, lo;
            hi.x = f2bf(o0); lo.x = f2bf(o0 - bf2f(hi.x));
            hi.y = f2bf(o1); lo.y = f2bf(o1 - bf2f(hi.y));
            hi.z = f2bf(o2); lo.z = f2bf(o2 - bf2f(hi.z));
            hi.w = f2bf(o3); lo.w = f2bf(o3 - bf2f(hi.w));
            *reinterpret_cast<ushort4*>(&outB[(size_t)node * (2 * HF) + lane * 4]) = hi;
            *reinterpret_cast<ushort4*>(&outB[(size_t)node * (2 * HF) + HF + lane * 4]) = lo;
        } else {
            *reinterpret_cast<float4*>(&outF[(size_t)node * HF + lane * 4]) =
                make_float4(o0, o1, o2, o3);
        }
    } else if (lane < HF) {
        float o = acc0 * inv + Res[(size_t)node * HF + lane];
        if (DO_ELU) o = (o > 0.f) ? o : expm1f(o);
        outF[(size_t)node * HF + lane] = o;
    }
}

// ---------------------------------------------------------------------------
extern "C" void kernel_launch(void* const* d_in, const int* in_sizes, int n_in,
                              void* d_out, int out_size, void* d_ws, size_t ws_size,
                              hipStream_t stream)
{
    const float* feat = (const float*)d_in[0];
    const int* src = (const int*)d_in[1];
    const int* dst = (const int*)d_in[2];
    const float* W0 = (const float*)d_in[3];
    const float* al0 = (const float*)d_in[4];
    const float* ar0 = (const float*)d_in[5];
    const float* rW0 = (const float*)d_in[6];
    const float* W1 = (const float*)d_in[7];
    const float* al1 = (const float*)d_in[8];
    const float* ar1 = (const float*)d_in[9];
    const float* rW1 = (const float*)d_in[10];
    const float* W2 = (const float*)d_in[11];
    const float* al2 = (const float*)d_in[12];
    const float* ar2 = (const float*)d_in[13];
    const float* rW2 = (const float*)d_in[14];
    float* out = (float*)d_out;

    char* ws = (char*)d_ws;
    size_t o = 0;
    auto alloc = [&](size_t bytes) -> void* {
        void* p = ws + o;
        o += (bytes + 255) & ~(size_t)255;
        return p;
    };
    unsigned short* A2 = (unsigned short*)alloc((size_t)NN * 512 * 2);  // hi|lo acts
    unsigned short* bufH = (unsigned short*)alloc((size_t)NN * 256 * 2);  // h (bf16)
    float* bufR = (float*)alloc((size_t)NN * 256 * 4);                    // residual
    unsigned short* W0s = (unsigned short*)alloc((size_t)256 * 256 * 2);
    unsigned short* rW0s = (unsigned short*)alloc((size_t)256 * 256 * 2);
    unsigned short* W1s = (unsigned short*)alloc((size_t)256 * 512 * 2);
    unsigned short* rW1s = (unsigned short*)alloc((size_t)256 * 512 * 2);
    unsigned short* W2s = (unsigned short*)alloc((size_t)40 * 512 * 2);
    unsigned short* rW2s = (unsigned short*)alloc((size_t)40 * 512 * 2);
    float* el = (float*)alloc((size_t)NN * 4 * 4);
    float* er = (float*)alloc((size_t)NN * 4 * 4);
    int* deg = (int*)alloc((size_t)NN * 4);
    int* offs = (int*)alloc((size_t)(NN + 1) * 4);
    int* cursor = (int*)alloc((size_t)NN * 4);
    int* psum = (int*)alloc((size_t)64 * 4);
    int* csrc = (int*)alloc((size_t)NE * 4);

    // ---- all splits upfront (feat + weights; activations fused into agg) ----
    const dim3 splitG(768, 1, 3);
    split3_kernel<<<splitG, 256, 0, stream>>>(feat, A2, NN * 128, 7,
                                              W0, W0s, 256 * 128, 7,
                                              rW0, rW0s, 256 * 128, 7);
    split3_kernel<<<splitG, 256, 0, stream>>>(W1, W1s, 256 * 256, 8,
                                              rW1, rW1s, 256 * 256, 8,
                                              W2, W2s, 40 * 256, 8);
    split3_kernel<<<splitG, 256, 0, stream>>>(rW2, rW2s, 40 * 256, 8,
                                              rW2, rW2s, 0, 8,
                                              rW2, rW2s, 0, 8);

    // ---- CSR build (by dst), shared across all 3 layers ----
    const int nb = (NN + 1023) / 1024;  // 49
    hipMemsetAsync(deg, 0, NN * sizeof(int), stream);
    hist_kernel<<<(NE + 255) / 256, 256, 0, stream>>>(dst, deg, NE);
    scan_part<<<nb, 1024, 0, stream>>>(deg, psum, NN);
    scan_tops<<<1, 64, 0, stream>>>(psum, offs, nb, NN);
    scan_final<<<nb, 1024, 0, stream>>>(deg, psum, offs, cursor, NN);
    scatter_kernel<<<(NE + 255) / 256, 256, 0, stream>>>(src, dst, cursor, csrc, NE);

    const int nodeBlocks = (NN + 3) / 4;
    const int gx = (NN + 127) / 128;  // 391

    // ---- layer 0: K=128 (K'=384, 6 steps), NcW=256, H=4, F=64 ----
    {
        dim3 g(gx, 4);
        gemm_lds<<<g, 256, 0, stream>>>(A2, W0s, rW0s, bufH, bufR, al0, ar0, el, er,
                                        NN, 128, 256, 256, 256, 256, 256, 4, 64, 6);
        gat_agg<4, 64, true, true><<<nodeBlocks, 256, 0, stream>>>(
            bufH, el, er, offs, csrc, bufR, nullptr, A2, NN);
    }
    // ---- layer 1: K=256 (K'=768, 12 steps), NcW=256, H=4, F=64 ----
    {
        dim3 g(gx, 4);
        gemm_lds<<<g, 256, 0, stream>>>(A2, W1s, rW1s, bufH, bufR, al1, ar1, el, er,
                                        NN, 256, 256, 512, 512, 256, 256, 4, 64, 12);
        gat_agg<4, 64, true, true><<<nodeBlocks, 256, 0, stream>>>(
            bufH, el, er, offs, csrc, bufR, nullptr, A2, NN);
    }
    // ---- layer 2: K=256 (K'=768, 12 steps), NcW=40, H=1, F=40 ----
    {
        dim3 g(gx, 1);
        gemm_lds<<<g, 256, 0, stream>>>(A2, W2s, rW2s, bufH, out, al2, ar2, el, er,
                                        NN, 256, 40, 512, 512, 40, 40, 1, 40, 12);
        gat_agg<1, 40, false, false><<<nodeBlocks, 256, 0, stream>>>(
            bufH, el, er, offs, csrc, out, out, nullptr, NN);
    }
}